// Round 9
// baseline (110.776 us; speedup 1.0000x reference)
//
#include <hip/hip_runtime.h>
#include <math.h>

#define Bb 2
#define Ss 1500
#define SP 1536   // padded rows per batch (24 tiles of 64)
#define Nn 1280
#define Hh 20
#define Rr 32
#define NT 24     // key tiles of 64

#define LOG2E 1.44269504088896f

typedef __attribute__((ext_vector_type(8))) short short8;
typedef __attribute__((ext_vector_type(4))) float f32x4;
typedef unsigned short ushort_t;

__device__ __forceinline__ unsigned short f2bf(float f) {
  unsigned u = __float_as_uint(f);
  u += 0x7fffu + ((u >> 16) & 1u);
  return (unsigned short)(u >> 16);
}
__device__ __forceinline__ float bf2f(unsigned short u) {
  return __uint_as_float((unsigned)u << 16);
}
__device__ __forceinline__ unsigned cvtpk(float a, float b) {
  unsigned d;
  asm("v_cvt_pk_bf16_f32 %0, %1, %2" : "=v"(d) : "v"(a), "v"(b));
  return d;  // lo16=bf16(a), hi16=bf16(b), RNE
}
__device__ __forceinline__ float fexp2(float x) {
  float r;
  asm("v_exp_f32 %0, %1" : "=v"(r) : "v"(x));
  return r;
}

__device__ __forceinline__ void gload16(const void* g, void* l) {
  __builtin_amdgcn_global_load_lds((const __attribute__((address_space(1))) unsigned int*)g,
                                   (__attribute__((address_space(3))) unsigned int*)l, 16, 0, 0);
}
__device__ __forceinline__ void gload4(const void* g, void* l) {
  __builtin_amdgcn_global_load_lds((const __attribute__((address_space(1))) unsigned int*)g,
                                   (__attribute__((address_space(3))) unsigned int*)l, 4, 0, 0);
}

#define BAR()                                  \
  do {                                         \
    asm volatile("" ::: "memory");             \
    __builtin_amdgcn_s_barrier();              \
    asm volatile("" ::: "memory");             \
  } while (0)

#define VMW(n) asm volatile("s_waitcnt vmcnt(" #n ")" ::: "memory")

// ---------------------------------------------------------------------------
// ws layout (float offsets):
//   wm     0        (20480)    fp32 Wq2h@Wk2h * 0.125*log2e
//   b2s    20480    (640)      fp32 bq@Wk2h * 0.125*log2e
//   xpq    21120    (96000)    fp32 q1 [3000][32]
//   kb     117120   (61440)    fp32 [40][1536], -1e30 pad
//   tbuf   178560   (96000)    fp32 [3000][32]
//   qhb    274560   (983040)   bf16 [40][1536][32]
//   k1b    1257600  (49152)    bf16 [2][1536][32]
//   v1b    1306752  (49152)    bf16 [2][32][1536]
//   xb     1355904  (1966080)  bf16 [3072][1280]
//   wcatb  3321984  (81920)    bf16 [128][1280] (q|k|v|0)
//   wo1b   3403904  (40960)    bf16 [64][1280]  (Wo1|0)
//   wv2b   3444864  (20480)    bf16 [1280][32]
//   wvb    3465344  (1966080)  bf16 [3072][1280]
//   pv1p   5431424  (3932160)  fp32 [2*20*24 tiles][2 jh][64 q][32 r]
//   psump  9363584  (122880)   fp32 [tiles][2 jh][64 q]
//   end    9486464 floats = 38 MB
// ---------------------------------------------------------------------------

// merged prep: blocks [0,1920): cast x; [1920,2060): cast weights; [2060,2080): wm/b2s
__global__ void prep_kernel(const float* __restrict__ x, const float* __restrict__ Wq1,
                            const float* __restrict__ Wk1, const float* __restrict__ Wv1,
                            const float* __restrict__ Wo1, const float* __restrict__ Wq2,
                            const float* __restrict__ Wk2, const float* __restrict__ Wv2,
                            const float* __restrict__ bq, ushort_t* __restrict__ xb,
                            ushort_t* __restrict__ wcatb, ushort_t* __restrict__ wo1b,
                            ushort_t* __restrict__ wv2b, float* __restrict__ wm,
                            float* __restrict__ b2s) {
  int bid = blockIdx.x, tid = threadIdx.x;
  __shared__ float q2s[2048], k2s[2048], bqs[64];
  if (bid < 1920) {
    int gid = bid * 256 + tid;  // 491520 = 3072*160
    int gr = gid / 160, c8 = gid % 160;
    int b = gr / SP, i = gr - b * SP;
    short8 v = (short8){0, 0, 0, 0, 0, 0, 0, 0};
    if (i < Ss) {
      const float* src = x + ((size_t)(b * Ss + i)) * 1280 + c8 * 8;
      float4 a0 = *(const float4*)src;
      float4 a1 = *(const float4*)(src + 4);
      v[0] = (short)f2bf(a0.x); v[1] = (short)f2bf(a0.y);
      v[2] = (short)f2bf(a0.z); v[3] = (short)f2bf(a0.w);
      v[4] = (short)f2bf(a1.x); v[5] = (short)f2bf(a1.y);
      v[6] = (short)f2bf(a1.z); v[7] = (short)f2bf(a1.w);
    }
    *(short8*)(xb + (size_t)gr * 1280 + c8 * 8) = v;
  } else if (bid < 2060) {
    int gid = (bid - 1920) * 256 + tid;  // 35840
    const float* src = nullptr;
    ushort_t* dst = nullptr;
    if (gid < 20480) {
      int row = gid / 160, c8 = gid % 160;
      dst = wcatb + (size_t)row * 1280 + c8 * 8;
      if (row < 32) src = Wq1 + (size_t)row * 1280 + c8 * 8;
      else if (row < 64) src = Wk1 + (size_t)(row - 32) * 1280 + c8 * 8;
      else if (row < 96) src = Wv1 + (size_t)(row - 64) * 1280 + c8 * 8;
    } else if (gid < 30720) {
      int g = gid - 20480;
      int row = g / 160, c8 = g % 160;
      dst = wo1b + (size_t)row * 1280 + c8 * 8;
      if (row < 32) src = Wo1 + (size_t)row * 1280 + c8 * 8;
    } else {
      int g = gid - 30720;
      int row = g >> 2, c8 = g & 3;
      dst = wv2b + row * 32 + c8 * 8;
      src = Wv2 + row * 32 + c8 * 8;
    }
    short8 v = (short8){0, 0, 0, 0, 0, 0, 0, 0};
    if (src) {
      #pragma unroll
      for (int j = 0; j < 8; ++j) v[j] = (short)f2bf(src[j]);
    }
    *(short8*)dst = v;
  } else {
    int h = bid - 2060;
    for (int e = tid; e < 2048; e += 256) {
      q2s[e] = Wq2[h * 2048 + e];
      k2s[e] = Wk2[h * 2048 + e];
    }
    if (tid < 64) bqs[tid] = bq[h * 64 + tid];
    __syncthreads();
    for (int e = tid; e < 1024; e += 256) {
      int r = e >> 5, t = e & 31;
      float s = 0.f;
      #pragma unroll 16
      for (int d = 0; d < 64; ++d) s += q2s[d * 32 + r] * k2s[d * 32 + t];
      wm[h * 1024 + r * 32 + t] = s * (0.125f * LOG2E);  // exp2-direct scaling
    }
    if (tid < 32) {
      float s = 0.f;
      #pragma unroll 16
      for (int d = 0; d < 64; ++d) s += bqs[d] * k2s[d * 32 + tid];
      b2s[h * 32 + tid] = s * (0.125f * LOG2E);
    }
  }
}

// GEMM: xb[3072x1280]bf16 @ wcat[96x1280]^T -> q1 fp32 / k1 bf16 / v1T bf16
// rowtile 32, 2 waves x 16 rows x 6 frags, BK=64, XOR-swizzled LDS.
__global__ __launch_bounds__(128) void gemm_qkv_kernel(
    const ushort_t* __restrict__ xbg, const ushort_t* __restrict__ wcat,
    float* __restrict__ xpq, ushort_t* __restrict__ k1b, ushort_t* __restrict__ v1b) {
  int tid = threadIdx.x, w = tid >> 6, l = tid & 63, l15 = l & 15, l4 = l >> 4;
  int row0 = blockIdx.x * 32;
  __shared__ __align__(16) short As[2][2048];  // [32][64] swz
  __shared__ __align__(16) short Bs[2][6144];  // [96][64] swz
  int sw8 = (((l & 7) ^ ((l >> 3) & 7)) << 3);  // pre-swizzled chunk for staging
  const ushort_t* asrc0 = xbg + (size_t)(row0 + w * 16 + (l >> 3)) * 1280 + sw8;
  const ushort_t* asrc1 = asrc0 + (size_t)8 * 1280;
  const ushort_t* bsrc[6];
  #pragma unroll
  for (int g = 0; g < 6; ++g)
    bsrc[g] = wcat + (size_t)(w * 48 + g * 8 + (l >> 3)) * 1280 + sw8;

#define QSTAGE(bufi, kk)                                            \
  do {                                                              \
    gload16(asrc0 + (kk), &As[bufi][w * 1024]);                     \
    gload16(asrc1 + (kk), &As[bufi][w * 1024 + 512]);               \
    gload16(bsrc[0] + (kk), &Bs[bufi][w * 3072]);                   \
    gload16(bsrc[1] + (kk), &Bs[bufi][w * 3072 + 512]);             \
    gload16(bsrc[2] + (kk), &Bs[bufi][w * 3072 + 1024]);            \
    gload16(bsrc[3] + (kk), &Bs[bufi][w * 3072 + 1536]);            \
    gload16(bsrc[4] + (kk), &Bs[bufi][w * 3072 + 2048]);            \
    gload16(bsrc[5] + (kk), &Bs[bufi][w * 3072 + 2560]);            \
  } while (0)

  f32x4 acc[6];
  #pragma unroll
  for (int nf = 0; nf < 6; ++nf) acc[nf] = (f32x4){0.f, 0.f, 0.f, 0.f};

  QSTAGE(0, 0);
  int cur = 0;
  for (int t = 0; t < 20; ++t) {
    if (t < 19) {
      QSTAGE(cur ^ 1, (t + 1) * 64);
      VMW(8);
    } else {
      VMW(0);
    }
    BAR();
    #pragma unroll
    for (int ks = 0; ks < 2; ++ks) {
      short8 af = *(const short8*)&As[cur][(w * 16 + l15) * 64 +
                                           (((ks * 4 + l4) ^ (l15 & 7)) << 3)];
      #pragma unroll
      for (int nf = 0; nf < 6; ++nf) {
        short8 bf = *(const short8*)&Bs[cur][(nf * 16 + l15) * 64 +
                                             (((ks * 4 + l4) ^ (l15 & 7)) << 3)];
        acc[nf] = __builtin_amdgcn_mfma_f32_16x16x32_bf16(af, bf, acc[nf], 0, 0, 0);
      }
    }
    BAR();
    cur ^= 1;
  }
#undef QSTAGE

  #pragma unroll
  for (int nf = 0; nf < 6; ++nf) {
    int o = nf * 16 + l15;
    #pragma unroll
    for (int reg = 0; reg < 4; ++reg) {
      int gr = row0 + w * 16 + l4 * 4 + reg;
      int b = (gr >= SP) ? 1 : 0;
      int i = gr - b * SP;
      if (i < Ss) {
        float v = acc[nf][reg];
        if (o < 32) xpq[((size_t)b * Ss + i) * 32 + o] = v;
        else if (o < 64) k1b[((size_t)b * SP + i) * 32 + (o - 32)] = f2bf(v);
        else v1b[((size_t)b * 32 + (o - 64)) * SP + i] = f2bf(v);
      }
    }
  }
}

// merged: blockIdx.y<20 -> qh (per i-tile,h,b); blockIdx.y==20 -> kb (per j-tile,b)
__global__ void qh_kb_kernel(const float* __restrict__ xpq, const float* __restrict__ wm,
                             const float* __restrict__ b2s, const ushort_t* __restrict__ k1b,
                             ushort_t* __restrict__ qhb, float* __restrict__ kbp) {
  int tid = threadIdx.x, b = blockIdx.z;
  if (blockIdx.y == 20) {
    int j0 = blockIdx.x * 64;
    __shared__ float k1s[64 * 33];
    __shared__ float b2sh[20 * 33];
    for (int e = tid; e < 2048; e += 256) {
      int row = e >> 5, t = e & 31;
      k1s[row * 33 + t] = bf2f(k1b[((size_t)b * SP + j0 + row) * 32 + t]);
    }
    for (int e = tid; e < 640; e += 256) b2sh[(e >> 5) * 33 + (e & 31)] = b2s[e];
    __syncthreads();
    for (int e = tid; e < 1280; e += 256) {
      int h = e >> 6, rw = e & 63;
      int j = j0 + rw;
      float s = -1e30f;
      if (j < Ss) {
        s = 0.f;
        #pragma unroll 8
        for (int t = 0; t < 32; ++t) s += k1s[rw * 33 + t] * b2sh[h * 33 + t];
      }
      kbp[((size_t)b * Hh + h) * SP + j] = s;
    }
  } else {
    int it = blockIdx.x, h = blockIdx.y;
    int i0 = it * 64;
    __shared__ float q1s[64 * 33];
    __shared__ float wms[1024];
    for (int e = tid; e < 2048; e += 256) {
      int row = e >> 5, r = e & 31;
      int i = i0 + row;
      q1s[row * 33 + r] = (i < Ss) ? xpq[((size_t)b * Ss + i) * 32 + r] : 0.f;
    }
    for (int e = tid; e < 1024; e += 256) wms[e] = wm[h * 1024 + e];
    __syncthreads();
    int row = tid >> 2, tc = (tid & 3) * 8;
    float o[8];
    #pragma unroll
    for (int j = 0; j < 8; ++j) o[j] = 0.f;
    for (int r = 0; r < 32; ++r) {
      float qv = q1s[row * 33 + r];
      #pragma unroll
      for (int j = 0; j < 8; ++j) o[j] += qv * wms[r * 32 + tc + j];
    }
    short8 sv;
    #pragma unroll
    for (int j = 0; j < 8; ++j) sv[j] = (short)f2bf(o[j]);
    *(short8*)(qhb + ((size_t)(b * Hh + h) * SP + i0 + row) * 32 + tc) = sv;
  }
}

// Attention, j-split x2: loop body identical to verified round-8 version.
// Writes raw fp32 PV1 partials + psum partials; PV2/normalize in combine_kernel.
__global__ __launch_bounds__(256) void attn_split_kernel(
    const ushort_t* __restrict__ qhg, const ushort_t* __restrict__ k1g,
    const ushort_t* __restrict__ v1g, const float* __restrict__ kbg,
    float* __restrict__ pv1p, float* __restrict__ psump) {
  int it = blockIdx.x, h = blockIdx.y, z = blockIdx.z;
  int b = z >> 1, jh = z & 1;
  int bh = b * Hh + h;
  int i0 = it * 64;
  int tid = threadIdx.x, w = tid >> 6, l = tid & 63;
  int l15 = l & 15, l4 = l >> 4;

  __shared__ short kS[2][2048];  // [kchunk(4)][key(64)][8]
  __shared__ short vS[2][2048];  // [r(32)][jslot(8)^swz][8]
  __shared__ float kbS[2][64];
  __shared__ short pS[4][1024];  // per-wave P [q(16)][key-slot swz]

  // resident A-frag: Qh[q=l15][k=l4*8+e]
  short8 qa = *(const short8*)(qhg + ((size_t)bh * SP + i0 + w * 16 + l15) * 32 + l4 * 8);
  VMW(0);  // qa landed; vmcnt counting below exact

  const ushort_t* ksrc = k1g + (size_t)b * SP * 32 + l * 32 + w * 8;
  const ushort_t* vsrc =
      v1g + ((size_t)b * 32 + w * 8 + (l >> 3)) * SP + (((l & 7) ^ ((l >> 3) & 7)) << 3);
  const float* kbsrc = kbg + (size_t)bh * SP + l;

#define STAGE(bufi, tt)                                   \
  do {                                                    \
    int j0s = (tt) * 64;                                  \
    gload16(ksrc + (size_t)j0s * 32, &kS[bufi][w * 512]); \
    gload16(vsrc + j0s, &vS[bufi][w * 512]);              \
    if (w == 0) gload4(kbsrc + j0s, &kbS[bufi][0]);       \
  } while (0)

  int base = jh * 12;
  STAGE(0, base);

  f32x4 pv1[2];
  pv1[0] = (f32x4){0.f, 0.f, 0.f, 0.f};
  pv1[1] = (f32x4){0.f, 0.f, 0.f, 0.f};
  float psr[4] = {0.f, 0.f, 0.f, 0.f};
  const f32x4 zf = (f32x4){0.f, 0.f, 0.f, 0.f};

  int cur = 0;
  for (int tt = 0; tt < 12; ++tt) {
    if (tt < 11) {
      STAGE(cur ^ 1, base + tt + 1);
      if (w == 0) VMW(3); else VMW(2);
    } else {
      VMW(0);
    }
    BAR();

    // S = Qh @ K1^T (+kb), exp2, pack to per-wave P (b16 low-half writes)
    #pragma unroll
    for (int nb = 0; nb < 4; ++nb) {
      short8 kf = *(const short8*)&kS[cur][l4 * 512 + (nb * 16 + l15) * 8];
      f32x4 c = __builtin_amdgcn_mfma_f32_16x16x32_bf16(qa, kf, zf, 0, 0, 0);
      float kbv = kbS[cur][nb * 16 + l15];
      int slot_lo = nb * 2 + (l15 >> 3);
      #pragma unroll
      for (int reg = 0; reg < 4; ++reg) {
        int q = l4 * 4 + reg;
        float p = fexp2(c[reg] + kbv);
        psr[reg] += p;
        pS[w][q * 64 + ((slot_lo ^ (q & 7)) << 3) + (l15 & 7)] = (short)cvtpk(p, p);
      }
    }

    // PV1 += P @ v1 (16q x 32r), fp32 accumulation across tiles
    #pragma unroll
    for (int kh = 0; kh < 2; ++kh) {
      short8 pa = *(const short8*)&pS[w][l15 * 64 + (((kh * 4 + l4) ^ (l15 & 7)) << 3)];
      #pragma unroll
      for (int nf = 0; nf < 2; ++nf) {
        short8 vf =
            *(const short8*)&vS[cur][(nf * 16 + l15) * 64 + (((kh * 4 + l4) ^ (l15 & 7)) << 3)];
        pv1[nf] = __builtin_amdgcn_mfma_f32_16x16x32_bf16(pa, vf, pv1[nf], 0, 0, 0);
      }
    }

    BAR();
    cur ^= 1;
  }
#undef STAGE

  // psum partial: reduce over the 16-lane key group
  #pragma unroll
  for (int reg = 0; reg < 4; ++reg) {
    #pragma unroll
    for (int m = 1; m < 16; m <<= 1) psr[reg] += __shfl_xor(psr[reg], m, 64);
  }

  size_t tix = (size_t)bh * 24 + it;
  float* pvdst = pv1p + tix * 4096 + (size_t)jh * 2048;
  #pragma unroll
  for (int nf = 0; nf < 2; ++nf) {
    #pragma unroll
    for (int reg = 0; reg < 4; ++reg) {
      pvdst[(w * 16 + l4 * 4 + reg) * 32 + nf * 16 + l15] = pv1[nf][reg];
    }
  }
  if (l15 == 0) {
    float* pd = psump + tix * 128 + jh * 64 + w * 16 + l4 * 4;
    #pragma unroll
    for (int reg = 0; reg < 4; ++reg) pd[reg] = psr[reg];
  }
}

// combine: sum j-half partials, PV2 in fp32 VALU, normalize, +bv, write bf16 wvb
__global__ __launch_bounds__(256) void combine_kernel(
    const float* __restrict__ pv1p, const float* __restrict__ psump,
    const ushort_t* __restrict__ wv2g, const float* __restrict__ bv,
    ushort_t* __restrict__ wvb) {
  int it = blockIdx.x, h = blockIdx.y, b = blockIdx.z;
  size_t tix = (size_t)(b * Hh + h) * 24 + it;
  int tid = threadIdx.x;
  __shared__ __align__(16) float pv[64 * 36];
  __shared__ __align__(16) float wv2f[32 * 68];
  __shared__ float ps[64];

  const float* src = pv1p + tix * 4096;
  for (int e = tid; e < 2048; e += 256) {
    int q = e >> 5, r = e & 31;
    pv[q * 36 + r] = src[e] + src[2048 + e];
  }
  for (int e = tid; e < 2048; e += 256) {
    int d = e >> 5, r = e & 31;
    wv2f[r * 68 + d] = bf2f(wv2g[h * 2048 + e]);
  }
  if (tid < 64) ps[tid] = psump[tix * 128 + tid] + psump[tix * 128 + 64 + tid];
  __syncthreads();

  int q = tid >> 2, dg = tid & 3;
  float pvr[32];
  #pragma unroll
  for (int c = 0; c < 8; ++c) {
    float4 v = *(const float4*)&pv[q * 36 + c * 4];
    pvr[c * 4 + 0] = v.x; pvr[c * 4 + 1] = v.y;
    pvr[c * 4 + 2] = v.z; pvr[c * 4 + 3] = v.w;
  }
  float o[16];
  #pragma unroll
  for (int k = 0; k < 16; ++k) o[k] = 0.f;
  #pragma unroll 8
  for (int r = 0; r < 32; ++r) {
    float p = pvr[r];
    #pragma unroll
    for (int c = 0; c < 4; ++c) {
      float4 wv = *(const float4*)&wv2f[r * 68 + dg * 16 + c * 4];
      o[c * 4 + 0] += p * wv.x;
      o[c * 4 + 1] += p * wv.y;
      o[c * 4 + 2] += p * wv.z;
      o[c * 4 + 3] += p * wv.w;
    }
  }

  float inv = 1.f / ps[q];
  int qi = it * 64 + q;
  if (qi < Ss) {
    unsigned pk[8];
    #pragma unroll
    for (int m = 0; m < 8; ++m) {
      float b0 = bv[h * 64 + dg * 16 + 2 * m];
      float b1 = bv[h * 64 + dg * 16 + 2 * m + 1];
      pk[m] = cvtpk(o[2 * m] * inv + b0, o[2 * m + 1] * inv + b1);
    }
    unsigned* dst = (unsigned*)(wvb + ((size_t)b * SP + qi) * 1280 + h * 64 + dg * 16);
    *(uint4*)dst = make_uint4(pk[0], pk[1], pk[2], pk[3]);
    *(uint4*)(dst + 4) = make_uint4(pk[4], pk[5], pk[6], pk[7]);
  }
}

// GEMM: wvb[3072x1280]bf16 @ wo1b[32x1280]^T -> tbuf fp32, rowtile 32, BK=64
__global__ __launch_bounds__(128) void gemm_o1_kernel(const ushort_t* __restrict__ wvg,
                                                      const ushort_t* __restrict__ wo1,
                                                      float* __restrict__ tbuf) {
  int tid = threadIdx.x, w = tid >> 6, l = tid & 63, l15 = l & 15, l4 = l >> 4;
  int row0 = blockIdx.x * 32;
  __shared__ __align__(16) short As[2][2048];
  __shared__ __align__(16) short Bs[2][2048];
  int sw8 = (((l & 7) ^ ((l >> 3) & 7)) << 3);
  const ushort_t* asrc0 = wvg + (size_t)(row0 + w * 16 + (l >> 3)) * 1280 + sw8;
  const ushort_t* asrc1 = asrc0 + (size_t)8 * 1280;
  const ushort_t* bsrc = wo1 + (size_t)(w * 16 + (l >> 3)) * 1280 + sw8;
  const ushort_t* bsrc1 = bsrc + (size_t)8 * 1280;

#define OSTAGE(bufi, kk)                                 \
  do {                                                   \
    gload16(asrc0 + (kk), &As[bufi][w * 1024]);          \
    gload16(asrc1 + (kk), &As[bufi][w * 1024 + 512]);    \
    gload16(bsrc + (kk), &Bs[bufi][w * 1024]);           \
    gload16(bsrc1 + (kk), &Bs[bufi][w * 1024 + 512]);    \
  } while (0)

  f32x4 acc[2];
  acc[0] = (f32x4){0.f, 0.f, 0.f, 0.f};
  acc[1] = (f32x4){0.f, 0.f, 0.f, 0.f};
  OSTAGE(0, 0);
  int cur = 0;
  for (int t = 0; t < 20; ++t) {
    if (t < 19) {
      OSTAGE(cur ^ 1, (t + 1) * 64);
      VMW(4);
    } else {
      VMW(0);
    }
    BAR();
    #pragma unroll
    for (int ks = 0; ks < 2; ++ks) {
      short8 af = *(const short8*)&As[cur][(w * 16 + l15) * 64 +
                                           (((ks * 4 + l4) ^ (l15 & 7)) << 3)];
      #pragma unroll
      for (int nf = 0; nf < 2; ++nf) {
        short8 bf = *(const short8*)&Bs[cur][(nf * 16 + l15) * 64 +
                                             (((ks * 4 + l4) ^ (l15 & 7)) << 3)];
        acc[nf] = __builtin_amdgcn_mfma_f32_16x16x32_bf16(af, bf, acc[nf], 0, 0, 0);
      }
    }
    BAR();
    cur ^= 1;
  }
#undef OSTAGE

  #pragma unroll
  for (int nf = 0; nf < 2; ++nf) {
    int o = nf * 16 + l15;
    #pragma unroll
    for (int reg = 0; reg < 4; ++reg) {
      int gr = row0 + w * 16 + l4 * 4 + reg;
      int b = (gr >= SP) ? 1 : 0;
      int i = gr - b * SP;
      if (i < Ss) tbuf[((size_t)b * Ss + i) * 32 + o] = acc[nf][reg];
    }
  }
}

// out[row][n] = bo[n] + sum_o tbuf[row][o] * Wo2[n][o]
__global__ void proj_o2_kernel(const float* __restrict__ tbuf, const float* __restrict__ Wo2,
                               const float* __restrict__ bo, float* __restrict__ out) {
  int rb = blockIdx.x, nb = blockIdx.y, tid = threadIdx.x;
  int rowbase = rb * 16, n0 = nb * 256;
  __shared__ float ts[16 * 33];
  __shared__ float wos[256 * 33];
  for (int e = tid; e < 8192; e += 256) {
    int nloc = e >> 5, o = e & 31;
    wos[nloc * 33 + o] = Wo2[(size_t)(n0 + nloc) * 32 + o];
  }
  for (int e = tid; e < 512; e += 256) {
    int row = e >> 5, o = e & 31;
    int gr = rowbase + row;
    ts[row * 33 + o] = (gr < Bb * Ss) ? tbuf[(size_t)gr * 32 + o] : 0.f;
  }
  __syncthreads();
  int n = n0 + tid;
  float bias = bo[n];
  for (int row = 0; row < 16; ++row) {
    int gr = rowbase + row;
    if (gr >= Bb * Ss) break;
    float s = bias;
    #pragma unroll 8
    for (int o = 0; o < 32; ++o) s += ts[row * 33 + o] * wos[tid * 33 + o];
    out[(size_t)gr * 1280 + n] = s;
  }
}

extern "C" void kernel_launch(void* const* d_in, const int* in_sizes, int n_in,
                              void* d_out, int out_size, void* d_ws, size_t ws_size,
                              hipStream_t stream) {
  const float* x   = (const float*)d_in[0];
  const float* Wq1 = (const float*)d_in[1];
  const float* Wq2 = (const float*)d_in[2];
  const float* bq  = (const float*)d_in[3];
  const float* Wk1 = (const float*)d_in[4];
  const float* Wk2 = (const float*)d_in[5];
  // d_in[6] = bk : drops out of softmax (row-constant logit shift)
  const float* Wv1 = (const float*)d_in[7];
  const float* Wv2 = (const float*)d_in[8];
  const float* bv  = (const float*)d_in[9];
  const float* Wo1 = (const float*)d_in[10];
  const float* Wo2 = (const float*)d_in[11];
  const float* bo  = (const float*)d_in[12];
  float* out = (float*)d_out;
  float* ws  = (float*)d_ws;

  if (ws_size < (size_t)9486464 * sizeof(float)) return;

  float* wm    = ws;
  float* b2s   = ws + 20480;
  float* xpq   = ws + 21120;
  float* kb    = ws + 117120;
  float* tbuf  = ws + 178560;
  ushort_t* qhb   = (ushort_t*)(ws + 274560);
  ushort_t* k1b   = (ushort_t*)(ws + 1257600);
  ushort_t* v1b   = (ushort_t*)(ws + 1306752);
  ushort_t* xb    = (ushort_t*)(ws + 1355904);
  ushort_t* wcatb = (ushort_t*)(ws + 3321984);
  ushort_t* wo1b  = (ushort_t*)(ws + 3403904);
  ushort_t* wv2b  = (ushort_t*)(ws + 3444864);
  ushort_t* wvb   = (ushort_t*)(ws + 3465344);
  float* pv1p  = ws + 5431424;
  float* psump = ws + 9363584;

  prep_kernel<<<2080, 256, 0, stream>>>(x, Wq1, Wk1, Wv1, Wo1, Wq2, Wk2, Wv2, bq,
                                        xb, wcatb, wo1b, wv2b, wm, b2s);
  gemm_qkv_kernel<<<96, 128, 0, stream>>>(xb, wcatb, xpq, k1b, v1b);
  qh_kb_kernel<<<dim3(NT, 21, Bb), 256, 0, stream>>>(xpq, wm, b2s, k1b, qhb, kb);
  attn_split_kernel<<<dim3(NT, Hh, 4), 256, 0, stream>>>(qhb, k1b, v1b, kb, pv1p, psump);
  combine_kernel<<<dim3(NT, Hh, Bb), 256, 0, stream>>>(pv1p, psump, wv2b, bv, wvb);
  gemm_o1_kernel<<<96, 128, 0, stream>>>(wvb, wo1b, tbuf);
  proj_o2_kernel<<<dim3(188, 5), 256, 0, stream>>>(tbuf, Wo2, bo, out);
}

// Round 10
// 101.000 us; speedup vs baseline: 1.0968x; 1.0968x over previous
//
#include <hip/hip_runtime.h>
#include <math.h>

#define Bb 2
#define Ss 1500
#define SP 1536   // padded rows per batch (24 tiles of 64)
#define Nn 1280
#define Hh 20
#define Rr 32
#define NT 24     // key tiles of 64

#define LOG2E 1.44269504088896f

typedef __attribute__((ext_vector_type(8))) short short8;
typedef __attribute__((ext_vector_type(4))) float f32x4;
typedef unsigned short ushort_t;

__device__ __forceinline__ unsigned short f2bf(float f) {
  unsigned u = __float_as_uint(f);
  u += 0x7fffu + ((u >> 16) & 1u);
  return (unsigned short)(u >> 16);
}
__device__ __forceinline__ float bf2f(unsigned short u) {
  return __uint_as_float((unsigned)u << 16);
}
__device__ __forceinline__ unsigned cvtpk(float a, float b) {
  unsigned d;
  asm("v_cvt_pk_bf16_f32 %0, %1, %2" : "=v"(d) : "v"(a), "v"(b));
  return d;  // lo16=bf16(a), hi16=bf16(b), RNE
}
__device__ __forceinline__ float fexp2(float x) {
  float r;
  asm("v_exp_f32 %0, %1" : "=v"(r) : "v"(x));
  return r;
}

__device__ __forceinline__ void gload16(const void* g, void* l) {
  __builtin_amdgcn_global_load_lds((const __attribute__((address_space(1))) unsigned int*)g,
                                   (__attribute__((address_space(3))) unsigned int*)l, 16, 0, 0);
}
__device__ __forceinline__ void gload4(const void* g, void* l) {
  __builtin_amdgcn_global_load_lds((const __attribute__((address_space(1))) unsigned int*)g,
                                   (__attribute__((address_space(3))) unsigned int*)l, 4, 0, 0);
}

#define BAR()                                  \
  do {                                         \
    asm volatile("" ::: "memory");             \
    __builtin_amdgcn_s_barrier();              \
    asm volatile("" ::: "memory");             \
  } while (0)

#define VMW(n) asm volatile("s_waitcnt vmcnt(" #n ")" ::: "memory")

// ---------------------------------------------------------------------------
// ws layout (float offsets) — round-8 layout (j-split reverted):
//   wm     0        (20480)    fp32 Wq2h@Wk2h * 0.125*log2e
//   b2s    20480    (640)      fp32 bq@Wk2h * 0.125*log2e
//   xpq    21120    (96000)    fp32 q1 [3000][32]
//   kb     117120   (61440)    fp32 [40][1536], -1e30 pad
//   tbuf   178560   (96000)    fp32 [3000][32]
//   qhb    274560   (983040)   bf16 [40][1536][32]
//   k1b    1257600  (49152)    bf16 [2][1536][32]
//   v1b    1306752  (49152)    bf16 [2][32][1536]
//   xb     1355904  (1966080)  bf16 [3072][1280]
//   wcatb  3321984  (81920)    bf16 [128][1280] (q|k|v|0)
//   wo1b   3403904  (40960)    bf16 [64][1280]  (Wo1|0)
//   wv2b   3444864  (20480)    bf16 [1280][32]
//   wvb    3465344  (1966080)  bf16 [3072][1280]
//   end    5431424 floats = 21.7 MB
// ---------------------------------------------------------------------------

// merged prep: blocks [0,1920): cast x; [1920,2060): cast weights; [2060,2080): wm/b2s
__global__ void prep_kernel(const float* __restrict__ x, const float* __restrict__ Wq1,
                            const float* __restrict__ Wk1, const float* __restrict__ Wv1,
                            const float* __restrict__ Wo1, const float* __restrict__ Wq2,
                            const float* __restrict__ Wk2, const float* __restrict__ Wv2,
                            const float* __restrict__ bq, ushort_t* __restrict__ xb,
                            ushort_t* __restrict__ wcatb, ushort_t* __restrict__ wo1b,
                            ushort_t* __restrict__ wv2b, float* __restrict__ wm,
                            float* __restrict__ b2s) {
  int bid = blockIdx.x, tid = threadIdx.x;
  __shared__ float q2s[2048], k2s[2048], bqs[64];
  if (bid < 1920) {
    int gid = bid * 256 + tid;  // 491520 = 3072*160
    int gr = gid / 160, c8 = gid % 160;
    int b = gr / SP, i = gr - b * SP;
    short8 v = (short8){0, 0, 0, 0, 0, 0, 0, 0};
    if (i < Ss) {
      const float* src = x + ((size_t)(b * Ss + i)) * 1280 + c8 * 8;
      float4 a0 = *(const float4*)src;
      float4 a1 = *(const float4*)(src + 4);
      v[0] = (short)f2bf(a0.x); v[1] = (short)f2bf(a0.y);
      v[2] = (short)f2bf(a0.z); v[3] = (short)f2bf(a0.w);
      v[4] = (short)f2bf(a1.x); v[5] = (short)f2bf(a1.y);
      v[6] = (short)f2bf(a1.z); v[7] = (short)f2bf(a1.w);
    }
    *(short8*)(xb + (size_t)gr * 1280 + c8 * 8) = v;
  } else if (bid < 2060) {
    int gid = (bid - 1920) * 256 + tid;  // 35840
    const float* src = nullptr;
    ushort_t* dst = nullptr;
    if (gid < 20480) {
      int row = gid / 160, c8 = gid % 160;
      dst = wcatb + (size_t)row * 1280 + c8 * 8;
      if (row < 32) src = Wq1 + (size_t)row * 1280 + c8 * 8;
      else if (row < 64) src = Wk1 + (size_t)(row - 32) * 1280 + c8 * 8;
      else if (row < 96) src = Wv1 + (size_t)(row - 64) * 1280 + c8 * 8;
    } else if (gid < 30720) {
      int g = gid - 20480;
      int row = g / 160, c8 = g % 160;
      dst = wo1b + (size_t)row * 1280 + c8 * 8;
      if (row < 32) src = Wo1 + (size_t)row * 1280 + c8 * 8;
    } else {
      int g = gid - 30720;
      int row = g >> 2, c8 = g & 3;
      dst = wv2b + row * 32 + c8 * 8;
      src = Wv2 + row * 32 + c8 * 8;
    }
    short8 v = (short8){0, 0, 0, 0, 0, 0, 0, 0};
    if (src) {
      #pragma unroll
      for (int j = 0; j < 8; ++j) v[j] = (short)f2bf(src[j]);
    }
    *(short8*)dst = v;
  } else {
    int h = bid - 2060;
    for (int e = tid; e < 2048; e += 256) {
      q2s[e] = Wq2[h * 2048 + e];
      k2s[e] = Wk2[h * 2048 + e];
    }
    if (tid < 64) bqs[tid] = bq[h * 64 + tid];
    __syncthreads();
    for (int e = tid; e < 1024; e += 256) {
      int r = e >> 5, t = e & 31;
      float s = 0.f;
      #pragma unroll 16
      for (int d = 0; d < 64; ++d) s += q2s[d * 32 + r] * k2s[d * 32 + t];
      wm[h * 1024 + r * 32 + t] = s * (0.125f * LOG2E);  // exp2-direct scaling
    }
    if (tid < 32) {
      float s = 0.f;
      #pragma unroll 16
      for (int d = 0; d < 64; ++d) s += bqs[d] * k2s[d * 32 + tid];
      b2s[h * 32 + tid] = s * (0.125f * LOG2E);
    }
  }
}

// GEMM: xb[3072x1280]bf16 @ wcat[96x1280]^T -> q1 fp32 / k1 bf16 / v1T bf16
// rowtile 32, 2 waves x 16 rows x 6 frags, BK=64, XOR-swizzled LDS.
__global__ __launch_bounds__(128) void gemm_qkv_kernel(
    const ushort_t* __restrict__ xbg, const ushort_t* __restrict__ wcat,
    float* __restrict__ xpq, ushort_t* __restrict__ k1b, ushort_t* __restrict__ v1b) {
  int tid = threadIdx.x, w = tid >> 6, l = tid & 63, l15 = l & 15, l4 = l >> 4;
  int row0 = blockIdx.x * 32;
  __shared__ __align__(16) short As[2][2048];  // [32][64] swz
  __shared__ __align__(16) short Bs[2][6144];  // [96][64] swz
  int sw8 = (((l & 7) ^ ((l >> 3) & 7)) << 3);  // pre-swizzled chunk for staging
  const ushort_t* asrc0 = xbg + (size_t)(row0 + w * 16 + (l >> 3)) * 1280 + sw8;
  const ushort_t* asrc1 = asrc0 + (size_t)8 * 1280;
  const ushort_t* bsrc[6];
  #pragma unroll
  for (int g = 0; g < 6; ++g)
    bsrc[g] = wcat + (size_t)(w * 48 + g * 8 + (l >> 3)) * 1280 + sw8;

#define QSTAGE(bufi, kk)                                            \
  do {                                                              \
    gload16(asrc0 + (kk), &As[bufi][w * 1024]);                     \
    gload16(asrc1 + (kk), &As[bufi][w * 1024 + 512]);               \
    gload16(bsrc[0] + (kk), &Bs[bufi][w * 3072]);                   \
    gload16(bsrc[1] + (kk), &Bs[bufi][w * 3072 + 512]);             \
    gload16(bsrc[2] + (kk), &Bs[bufi][w * 3072 + 1024]);            \
    gload16(bsrc[3] + (kk), &Bs[bufi][w * 3072 + 1536]);            \
    gload16(bsrc[4] + (kk), &Bs[bufi][w * 3072 + 2048]);            \
    gload16(bsrc[5] + (kk), &Bs[bufi][w * 3072 + 2560]);            \
  } while (0)

  f32x4 acc[6];
  #pragma unroll
  for (int nf = 0; nf < 6; ++nf) acc[nf] = (f32x4){0.f, 0.f, 0.f, 0.f};

  QSTAGE(0, 0);
  int cur = 0;
  for (int t = 0; t < 20; ++t) {
    if (t < 19) {
      QSTAGE(cur ^ 1, (t + 1) * 64);
      VMW(8);
    } else {
      VMW(0);
    }
    BAR();
    #pragma unroll
    for (int ks = 0; ks < 2; ++ks) {
      short8 af = *(const short8*)&As[cur][(w * 16 + l15) * 64 +
                                           (((ks * 4 + l4) ^ (l15 & 7)) << 3)];
      #pragma unroll
      for (int nf = 0; nf < 6; ++nf) {
        short8 bf = *(const short8*)&Bs[cur][(nf * 16 + l15) * 64 +
                                             (((ks * 4 + l4) ^ (l15 & 7)) << 3)];
        acc[nf] = __builtin_amdgcn_mfma_f32_16x16x32_bf16(af, bf, acc[nf], 0, 0, 0);
      }
    }
    BAR();
    cur ^= 1;
  }
#undef QSTAGE

  #pragma unroll
  for (int nf = 0; nf < 6; ++nf) {
    int o = nf * 16 + l15;
    #pragma unroll
    for (int reg = 0; reg < 4; ++reg) {
      int gr = row0 + w * 16 + l4 * 4 + reg;
      int b = (gr >= SP) ? 1 : 0;
      int i = gr - b * SP;
      if (i < Ss) {
        float v = acc[nf][reg];
        if (o < 32) xpq[((size_t)b * Ss + i) * 32 + o] = v;
        else if (o < 64) k1b[((size_t)b * SP + i) * 32 + (o - 32)] = f2bf(v);
        else v1b[((size_t)b * 32 + (o - 64)) * SP + i] = f2bf(v);
      }
    }
  }
}

// merged: blockIdx.y<20 -> qh (per i-tile,h,b); blockIdx.y==20 -> kb (per j-tile,b)
__global__ void qh_kb_kernel(const float* __restrict__ xpq, const float* __restrict__ wm,
                             const float* __restrict__ b2s, const ushort_t* __restrict__ k1b,
                             ushort_t* __restrict__ qhb, float* __restrict__ kbp) {
  int tid = threadIdx.x, b = blockIdx.z;
  if (blockIdx.y == 20) {
    int j0 = blockIdx.x * 64;
    __shared__ float k1s[64 * 33];
    __shared__ float b2sh[20 * 33];
    for (int e = tid; e < 2048; e += 256) {
      int row = e >> 5, t = e & 31;
      k1s[row * 33 + t] = bf2f(k1b[((size_t)b * SP + j0 + row) * 32 + t]);
    }
    for (int e = tid; e < 640; e += 256) b2sh[(e >> 5) * 33 + (e & 31)] = b2s[e];
    __syncthreads();
    for (int e = tid; e < 1280; e += 256) {
      int h = e >> 6, rw = e & 63;
      int j = j0 + rw;
      float s = -1e30f;
      if (j < Ss) {
        s = 0.f;
        #pragma unroll 8
        for (int t = 0; t < 32; ++t) s += k1s[rw * 33 + t] * b2sh[h * 33 + t];
      }
      kbp[((size_t)b * Hh + h) * SP + j] = s;
    }
  } else {
    int it = blockIdx.x, h = blockIdx.y;
    int i0 = it * 64;
    __shared__ float q1s[64 * 33];
    __shared__ float wms[1024];
    for (int e = tid; e < 2048; e += 256) {
      int row = e >> 5, r = e & 31;
      int i = i0 + row;
      q1s[row * 33 + r] = (i < Ss) ? xpq[((size_t)b * Ss + i) * 32 + r] : 0.f;
    }
    for (int e = tid; e < 1024; e += 256) wms[e] = wm[h * 1024 + e];
    __syncthreads();
    int row = tid >> 2, tc = (tid & 3) * 8;
    float o[8];
    #pragma unroll
    for (int j = 0; j < 8; ++j) o[j] = 0.f;
    for (int r = 0; r < 32; ++r) {
      float qv = q1s[row * 33 + r];
      #pragma unroll
      for (int j = 0; j < 8; ++j) o[j] += qv * wms[r * 32 + tc + j];
    }
    short8 sv;
    #pragma unroll
    for (int j = 0; j < 8; ++j) sv[j] = (short)f2bf(o[j]);
    *(short8*)(qhb + ((size_t)(b * Hh + h) * SP + i0 + row) * 32 + tc) = sv;
  }
}

// Attention: round-8 verified loop body; this round's deltas:
//  - 3-buffer K/V rotation, ONE barrier per tile (order: VMW -> BAR -> compute -> STAGE)
//  - s_setprio(1) around the per-tile compute (T5)
__global__ __launch_bounds__(256) void attn2_kernel(
    const ushort_t* __restrict__ qhg, const ushort_t* __restrict__ k1g,
    const ushort_t* __restrict__ v1g, const ushort_t* __restrict__ wv2g,
    const float* __restrict__ kbg, const float* __restrict__ bv, ushort_t* __restrict__ wvb) {
  int it = blockIdx.x, h = blockIdx.y, b = blockIdx.z;
  int bh = b * Hh + h;
  int i0 = it * 64;
  int tid = threadIdx.x, w = tid >> 6, l = tid & 63;
  int l15 = l & 15, l4 = l >> 4;

  __shared__ short kS[3][2048];  // [kchunk(4)][key(64)][8]
  __shared__ short vS[3][2048];  // [r(32)][jslot(8)^swz][8]
  __shared__ float kbS[3][64];
  __shared__ short pS[4][1024];  // per-wave P [q(16)][key-slot swz]
  __shared__ short p2S[4][512];  // per-wave PV1 [q(16)][r-slot swz]

  // resident A-frag: Qh[q=l15][k=l4*8+e]
  short8 qa = *(const short8*)(qhg + ((size_t)bh * SP + i0 + w * 16 + l15) * 32 + l4 * 8);
  // resident B-frags: Wv2h[r=l4*8+e][d=db*16+l15]
  short8 wb0 = *(const short8*)(wv2g + (size_t)(h * 64 + 0 * 16 + l15) * 32 + l4 * 8);
  short8 wb1 = *(const short8*)(wv2g + (size_t)(h * 64 + 1 * 16 + l15) * 32 + l4 * 8);
  short8 wb2 = *(const short8*)(wv2g + (size_t)(h * 64 + 2 * 16 + l15) * 32 + l4 * 8);
  short8 wb3 = *(const short8*)(wv2g + (size_t)(h * 64 + 3 * 16 + l15) * 32 + l4 * 8);
  VMW(0);  // residents landed; manual vmcnt counting below is exact

  const ushort_t* ksrc = k1g + (size_t)b * SP * 32 + l * 32 + w * 8;
  const ushort_t* vsrc =
      v1g + ((size_t)b * 32 + w * 8 + (l >> 3)) * SP + (((l & 7) ^ ((l >> 3) & 7)) << 3);
  const float* kbsrc = kbg + (size_t)bh * SP + l;

#define STAGE(bufi, tt)                                   \
  do {                                                    \
    int j0s = (tt) * 64;                                  \
    gload16(ksrc + (size_t)j0s * 32, &kS[bufi][w * 512]); \
    gload16(vsrc + j0s, &vS[bufi][w * 512]);              \
    if (w == 0) gload4(kbsrc + j0s, &kbS[bufi][0]);       \
  } while (0)

  STAGE(0, 0);
  STAGE(1, 1);

  f32x4 pv1[2];
  pv1[0] = (f32x4){0.f, 0.f, 0.f, 0.f};
  pv1[1] = (f32x4){0.f, 0.f, 0.f, 0.f};
  float psr[4] = {0.f, 0.f, 0.f, 0.f};
  const f32x4 zf = (f32x4){0.f, 0.f, 0.f, 0.f};

  int cur = 0;   // compute buffer = t % 3
  for (int t = 0; t < NT; ++t) {
    // in flight here: stages {t, t+1} (t+2 issued after compute below).
    // Wait stage t complete, leave t+1 pending: w0 has 3 loads/stage, others 2.
    if (t < NT - 1) {
      if (w == 0) VMW(3); else VMW(2);
    } else {
      VMW(0);
    }
    BAR();

    __builtin_amdgcn_s_setprio(1);
    // S = Qh @ K1^T (+kb), exp2, pack to per-wave P (b16 low-half writes)
    #pragma unroll
    for (int nb = 0; nb < 4; ++nb) {
      short8 kf = *(const short8*)&kS[cur][l4 * 512 + (nb * 16 + l15) * 8];
      f32x4 c = __builtin_amdgcn_mfma_f32_16x16x32_bf16(qa, kf, zf, 0, 0, 0);
      float kbv = kbS[cur][nb * 16 + l15];
      int slot_lo = nb * 2 + (l15 >> 3);
      #pragma unroll
      for (int reg = 0; reg < 4; ++reg) {
        int q = l4 * 4 + reg;
        float p = fexp2(c[reg] + kbv);
        psr[reg] += p;
        pS[w][q * 64 + ((slot_lo ^ (q & 7)) << 3) + (l15 & 7)] = (short)cvtpk(p, p);
      }
    }

    // PV1 += P @ v1 (16q x 32r), fp32 accumulation across all tiles
    #pragma unroll
    for (int kh = 0; kh < 2; ++kh) {
      short8 pa = *(const short8*)&pS[w][l15 * 64 + (((kh * 4 + l4) ^ (l15 & 7)) << 3)];
      #pragma unroll
      for (int nf = 0; nf < 2; ++nf) {
        short8 vf =
            *(const short8*)&vS[cur][(nf * 16 + l15) * 64 + (((kh * 4 + l4) ^ (l15 & 7)) << 3)];
        pv1[nf] = __builtin_amdgcn_mfma_f32_16x16x32_bf16(pa, vf, pv1[nf], 0, 0, 0);
      }
    }
    __builtin_amdgcn_s_setprio(0);

    // stage tile t+2 into buffer (t+2)%3 — the buffer compute(t-1) just vacated;
    // all waves passed BAR(t) after finishing compute(t-1), so no race.
    if (t + 2 < NT) {
      int sb = (cur + 2 >= 3) ? cur - 1 : cur + 2;
      STAGE(sb, t + 2);
    }
    cur = (cur == 2) ? 0 : cur + 1;
  }
#undef STAGE

  // epilogue: relayout PV1 -> A-frag via per-wave LDS (once), then PV2
  #pragma unroll
  for (int nf = 0; nf < 2; ++nf) {
    #pragma unroll
    for (int reg = 0; reg < 4; ++reg) {
      int q = l4 * 4 + reg;
      int slot = nf * 2 + (l15 >> 3);
      p2S[w][q * 32 + ((slot ^ ((q >> 1) & 3)) << 3) + (l15 & 7)] =
          (short)cvtpk(pv1[nf][reg], pv1[nf][reg]);
    }
  }
  short8 pa2 = *(const short8*)&p2S[w][l15 * 32 + ((l4 ^ ((l15 >> 1) & 3)) << 3)];

  f32x4 acc[4];
  acc[0] = __builtin_amdgcn_mfma_f32_16x16x32_bf16(pa2, wb0, zf, 0, 0, 0);
  acc[1] = __builtin_amdgcn_mfma_f32_16x16x32_bf16(pa2, wb1, zf, 0, 0, 0);
  acc[2] = __builtin_amdgcn_mfma_f32_16x16x32_bf16(pa2, wb2, zf, 0, 0, 0);
  acc[3] = __builtin_amdgcn_mfma_f32_16x16x32_bf16(pa2, wb3, zf, 0, 0, 0);

  #pragma unroll
  for (int reg = 0; reg < 4; ++reg) {
    #pragma unroll
    for (int m = 1; m < 16; m <<= 1) psr[reg] += __shfl_xor(psr[reg], m, 64);
  }
  float inv[4];
  #pragma unroll
  for (int reg = 0; reg < 4; ++reg) inv[reg] = 1.f / psr[reg];

  #pragma unroll
  for (int db = 0; db < 4; ++db) {
    float bvv = bv[h * 64 + db * 16 + l15];
    #pragma unroll
    for (int reg = 0; reg < 4; ++reg) {
      int qi = i0 + w * 16 + l4 * 4 + reg;
      if (qi < Ss)
        wvb[((size_t)(b * SP + qi)) * 1280 + h * 64 + db * 16 + l15] =
            f2bf(acc[db][reg] * inv[reg] + bvv);
    }
  }
}

// GEMM: wvb[3072x1280]bf16 @ wo1b[32x1280]^T -> tbuf fp32, rowtile 32, BK=64
__global__ __launch_bounds__(128) void gemm_o1_kernel(const ushort_t* __restrict__ wvg,
                                                      const ushort_t* __restrict__ wo1,
                                                      float* __restrict__ tbuf) {
  int tid = threadIdx.x, w = tid >> 6, l = tid & 63, l15 = l & 15, l4 = l >> 4;
  int row0 = blockIdx.x * 32;
  __shared__ __align__(16) short As[2][2048];
  __shared__ __align__(16) short Bs[2][2048];
  int sw8 = (((l & 7) ^ ((l >> 3) & 7)) << 3);
  const ushort_t* asrc0 = wvg + (size_t)(row0 + w * 16 + (l >> 3)) * 1280 + sw8;
  const ushort_t* asrc1 = asrc0 + (size_t)8 * 1280;
  const ushort_t* bsrc = wo1 + (size_t)(w * 16 + (l >> 3)) * 1280 + sw8;
  const ushort_t* bsrc1 = bsrc + (size_t)8 * 1280;

#define OSTAGE(bufi, kk)                                 \
  do {                                                   \
    gload16(asrc0 + (kk), &As[bufi][w * 1024]);          \
    gload16(asrc1 + (kk), &As[bufi][w * 1024 + 512]);    \
    gload16(bsrc + (kk), &Bs[bufi][w * 1024]);           \
    gload16(bsrc1 + (kk), &Bs[bufi][w * 1024 + 512]);    \
  } while (0)

  f32x4 acc[2];
  acc[0] = (f32x4){0.f, 0.f, 0.f, 0.f};
  acc[1] = (f32x4){0.f, 0.f, 0.f, 0.f};
  OSTAGE(0, 0);
  int cur = 0;
  for (int t = 0; t < 20; ++t) {
    if (t < 19) {
      OSTAGE(cur ^ 1, (t + 1) * 64);
      VMW(4);
    } else {
      VMW(0);
    }
    BAR();
    #pragma unroll
    for (int ks = 0; ks < 2; ++ks) {
      short8 af = *(const short8*)&As[cur][(w * 16 + l15) * 64 +
                                           (((ks * 4 + l4) ^ (l15 & 7)) << 3)];
      #pragma unroll
      for (int nf = 0; nf < 2; ++nf) {
        short8 bf = *(const short8*)&Bs[cur][(nf * 16 + l15) * 64 +
                                             (((ks * 4 + l4) ^ (l15 & 7)) << 3)];
        acc[nf] = __builtin_amdgcn_mfma_f32_16x16x32_bf16(af, bf, acc[nf], 0, 0, 0);
      }
    }
    BAR();
    cur ^= 1;
  }
#undef OSTAGE

  #pragma unroll
  for (int nf = 0; nf < 2; ++nf) {
    int o = nf * 16 + l15;
    #pragma unroll
    for (int reg = 0; reg < 4; ++reg) {
      int gr = row0 + w * 16 + l4 * 4 + reg;
      int b = (gr >= SP) ? 1 : 0;
      int i = gr - b * SP;
      if (i < Ss) tbuf[((size_t)b * Ss + i) * 32 + o] = acc[nf][reg];
    }
  }
}

// out[row][n] = bo[n] + sum_o tbuf[row][o] * Wo2[n][o]
__global__ void proj_o2_kernel(const float* __restrict__ tbuf, const float* __restrict__ Wo2,
                               const float* __restrict__ bo, float* __restrict__ out) {
  int rb = blockIdx.x, nb = blockIdx.y, tid = threadIdx.x;
  int rowbase = rb * 16, n0 = nb * 256;
  __shared__ float ts[16 * 33];
  __shared__ float wos[256 * 33];
  for (int e = tid; e < 8192; e += 256) {
    int nloc = e >> 5, o = e & 31;
    wos[nloc * 33 + o] = Wo2[(size_t)(n0 + nloc) * 32 + o];
  }
  for (int e = tid; e < 512; e += 256) {
    int row = e >> 5, o = e & 31;
    int gr = rowbase + row;
    ts[row * 33 + o] = (gr < Bb * Ss) ? tbuf[(size_t)gr * 32 + o] : 0.f;
  }
  __syncthreads();
  int n = n0 + tid;
  float bias = bo[n];
  for (int row = 0; row < 16; ++row) {
    int gr = rowbase + row;
    if (gr >= Bb * Ss) break;
    float s = bias;
    #pragma unroll 8
    for (int o = 0; o < 32; ++o) s += ts[row * 33 + o] * wos[tid * 33 + o];
    out[(size_t)gr * 1280 + n] = s;
  }
}

extern "C" void kernel_launch(void* const* d_in, const int* in_sizes, int n_in,
                              void* d_out, int out_size, void* d_ws, size_t ws_size,
                              hipStream_t stream) {
  const float* x   = (const float*)d_in[0];
  const float* Wq1 = (const float*)d_in[1];
  const float* Wq2 = (const float*)d_in[2];
  const float* bq  = (const float*)d_in[3];
  const float* Wk1 = (const float*)d_in[4];
  const float* Wk2 = (const float*)d_in[5];
  // d_in[6] = bk : drops out of softmax (row-constant logit shift)
  const float* Wv1 = (const float*)d_in[7];
  const float* Wv2 = (const float*)d_in[8];
  const float* bv  = (const float*)d_in[9];
  const float* Wo1 = (const float*)d_in[10];
  const float* Wo2 = (const float*)d_in[11];
  const float* bo  = (const float*)d_in[12];
  float* out = (float*)d_out;
  float* ws  = (float*)d_ws;

  if (ws_size < (size_t)5431424 * sizeof(float)) return;

  float* wm    = ws;
  float* b2s   = ws + 20480;
  float* xpq   = ws + 21120;
  float* kb    = ws + 117120;
  float* tbuf  = ws + 178560;
  ushort_t* qhb   = (ushort_t*)(ws + 274560);
  ushort_t* k1b   = (ushort_t*)(ws + 1257600);
  ushort_t* v1b   = (ushort_t*)(ws + 1306752);
  ushort_t* xb    = (ushort_t*)(ws + 1355904);
  ushort_t* wcatb = (ushort_t*)(ws + 3321984);
  ushort_t* wo1b  = (ushort_t*)(ws + 3403904);
  ushort_t* wv2b  = (ushort_t*)(ws + 3444864);
  ushort_t* wvb   = (ushort_t*)(ws + 3465344);

  prep_kernel<<<2080, 256, 0, stream>>>(x, Wq1, Wk1, Wv1, Wo1, Wq2, Wk2, Wv2, bq,
                                        xb, wcatb, wo1b, wv2b, wm, b2s);
  gemm_qkv_kernel<<<96, 128, 0, stream>>>(xb, wcatb, xpq, k1b, v1b);
  qh_kb_kernel<<<dim3(NT, 21, Bb), 256, 0, stream>>>(xpq, wm, b2s, k1b, qhb, kb);
  attn2_kernel<<<dim3(NT, Hh, Bb), 256, 0, stream>>>(qhb, k1b, v1b, wv2b, kb, bv, wvb);
  gemm_o1_kernel<<<96, 128, 0, stream>>>(wvb, wo1b, tbuf);
  proj_o2_kernel<<<dim3(188, 5), 256, 0, stream>>>(tbuf, Wo2, bo, out);
}

// Round 11
// 99.157 us; speedup vs baseline: 1.1172x; 1.0186x over previous
//
#include <hip/hip_runtime.h>
#include <math.h>

#define Bb 2
#define Ss 1500
#define SP 1536   // padded rows per batch (24 tiles of 64)
#define Nn 1280
#define Hh 20
#define Rr 32
#define NT 24     // key tiles of 64

#define LOG2E 1.44269504088896f

typedef __attribute__((ext_vector_type(8))) short short8;
typedef __attribute__((ext_vector_type(4))) float f32x4;
typedef unsigned short ushort_t;

__device__ __forceinline__ unsigned short f2bf(float f) {
  unsigned u = __float_as_uint(f);
  u += 0x7fffu + ((u >> 16) & 1u);
  return (unsigned short)(u >> 16);
}
__device__ __forceinline__ float bf2f(unsigned short u) {
  return __uint_as_float((unsigned)u << 16);
}
__device__ __forceinline__ unsigned cvtpk(float a, float b) {
  unsigned d;
  asm("v_cvt_pk_bf16_f32 %0, %1, %2" : "=v"(d) : "v"(a), "v"(b));
  return d;  // lo16=bf16(a), hi16=bf16(b), RNE
}
__device__ __forceinline__ float fexp2(float x) {
  float r;
  asm("v_exp_f32 %0, %1" : "=v"(r) : "v"(x));
  return r;
}

__device__ __forceinline__ void gload16(const void* g, void* l) {
  __builtin_amdgcn_global_load_lds((const __attribute__((address_space(1))) unsigned int*)g,
                                   (__attribute__((address_space(3))) unsigned int*)l, 16, 0, 0);
}
__device__ __forceinline__ void gload4(const void* g, void* l) {
  __builtin_amdgcn_global_load_lds((const __attribute__((address_space(1))) unsigned int*)g,
                                   (__attribute__((address_space(3))) unsigned int*)l, 4, 0, 0);
}

#define BAR()                                  \
  do {                                         \
    asm volatile("" ::: "memory");             \
    __builtin_amdgcn_s_barrier();              \
    asm volatile("" ::: "memory");             \
  } while (0)

#define VMW(n) asm volatile("s_waitcnt vmcnt(" #n ")" ::: "memory")

// ---------------------------------------------------------------------------
// ws layout (float offsets) — unchanged (round-8/10 layout):
//   wm     0        (20480)    fp32 Wq2h@Wk2h * 0.125*log2e
//   b2s    20480    (640)      fp32 bq@Wk2h * 0.125*log2e
//   xpq    21120    (96000)    fp32 q1 [3000][32]
//   kb     117120   (61440)    fp32 [40][1536], -1e30 pad
//   tbuf   178560   (96000)    fp32 [3000][32]
//   qhb    274560   (983040)   bf16 [40][1536][32]
//   k1b    1257600  (49152)    bf16 [2][1536][32]
//   v1b    1306752  (49152)    bf16 [2][32][1536]
//   xb     1355904  (1966080)  bf16 [3072][1280]
//   wcatb  3321984  (81920)    bf16 [128][1280] (q|k|v|0)
//   wo1b   3403904  (40960)    bf16 [64][1280]  (Wo1|0)
//   wv2b   3444864  (20480)    bf16 [1280][32]
//   wvb    3465344  (1966080)  bf16 [3072][1280]
//   end    5431424 floats = 21.7 MB
// ---------------------------------------------------------------------------

// merged prep: blocks [0,1920): cast x; [1920,2060): cast weights; [2060,2080): wm/b2s
__global__ void prep_kernel(const float* __restrict__ x, const float* __restrict__ Wq1,
                            const float* __restrict__ Wk1, const float* __restrict__ Wv1,
                            const float* __restrict__ Wo1, const float* __restrict__ Wq2,
                            const float* __restrict__ Wk2, const float* __restrict__ Wv2,
                            const float* __restrict__ bq, ushort_t* __restrict__ xb,
                            ushort_t* __restrict__ wcatb, ushort_t* __restrict__ wo1b,
                            ushort_t* __restrict__ wv2b, float* __restrict__ wm,
                            float* __restrict__ b2s) {
  int bid = blockIdx.x, tid = threadIdx.x;
  __shared__ float q2s[2048], k2s[2048], bqs[64];
  if (bid < 1920) {
    int gid = bid * 256 + tid;  // 491520 = 3072*160
    int gr = gid / 160, c8 = gid % 160;
    int b = gr / SP, i = gr - b * SP;
    short8 v = (short8){0, 0, 0, 0, 0, 0, 0, 0};
    if (i < Ss) {
      const float* src = x + ((size_t)(b * Ss + i)) * 1280 + c8 * 8;
      float4 a0 = *(const float4*)src;
      float4 a1 = *(const float4*)(src + 4);
      v[0] = (short)f2bf(a0.x); v[1] = (short)f2bf(a0.y);
      v[2] = (short)f2bf(a0.z); v[3] = (short)f2bf(a0.w);
      v[4] = (short)f2bf(a1.x); v[5] = (short)f2bf(a1.y);
      v[6] = (short)f2bf(a1.z); v[7] = (short)f2bf(a1.w);
    }
    *(short8*)(xb + (size_t)gr * 1280 + c8 * 8) = v;
  } else if (bid < 2060) {
    int gid = (bid - 1920) * 256 + tid;  // 35840
    const float* src = nullptr;
    ushort_t* dst = nullptr;
    if (gid < 20480) {
      int row = gid / 160, c8 = gid % 160;
      dst = wcatb + (size_t)row * 1280 + c8 * 8;
      if (row < 32) src = Wq1 + (size_t)row * 1280 + c8 * 8;
      else if (row < 64) src = Wk1 + (size_t)(row - 32) * 1280 + c8 * 8;
      else if (row < 96) src = Wv1 + (size_t)(row - 64) * 1280 + c8 * 8;
    } else if (gid < 30720) {
      int g = gid - 20480;
      int row = g / 160, c8 = g % 160;
      dst = wo1b + (size_t)row * 1280 + c8 * 8;
      if (row < 32) src = Wo1 + (size_t)row * 1280 + c8 * 8;
    } else {
      int g = gid - 30720;
      int row = g >> 2, c8 = g & 3;
      dst = wv2b + row * 32 + c8 * 8;
      src = Wv2 + row * 32 + c8 * 8;
    }
    short8 v = (short8){0, 0, 0, 0, 0, 0, 0, 0};
    if (src) {
      #pragma unroll
      for (int j = 0; j < 8; ++j) v[j] = (short)f2bf(src[j]);
    }
    *(short8*)dst = v;
  } else {
    int h = bid - 2060;
    for (int e = tid; e < 2048; e += 256) {
      q2s[e] = Wq2[h * 2048 + e];
      k2s[e] = Wk2[h * 2048 + e];
    }
    if (tid < 64) bqs[tid] = bq[h * 64 + tid];
    __syncthreads();
    for (int e = tid; e < 1024; e += 256) {
      int r = e >> 5, t = e & 31;
      float s = 0.f;
      #pragma unroll 16
      for (int d = 0; d < 64; ++d) s += q2s[d * 32 + r] * k2s[d * 32 + t];
      wm[h * 1024 + r * 32 + t] = s * (0.125f * LOG2E);  // exp2-direct scaling
    }
    if (tid < 32) {
      float s = 0.f;
      #pragma unroll 16
      for (int d = 0; d < 64; ++d) s += bqs[d] * k2s[d * 32 + tid];
      b2s[h * 32 + tid] = s * (0.125f * LOG2E);
    }
  }
}

// GEMM: xb[3072x1280]bf16 @ wcat[96x1280]^T -> q1 fp32 / k1 bf16 / v1T bf16
// rowtile 32, 2 waves x 16 rows x 6 frags, BK=64, XOR-swizzled LDS.
__global__ __launch_bounds__(128) void gemm_qkv_kernel(
    const ushort_t* __restrict__ xbg, const ushort_t* __restrict__ wcat,
    float* __restrict__ xpq, ushort_t* __restrict__ k1b, ushort_t* __restrict__ v1b) {
  int tid = threadIdx.x, w = tid >> 6, l = tid & 63, l15 = l & 15, l4 = l >> 4;
  int row0 = blockIdx.x * 32;
  __shared__ __align__(16) short As[2][2048];  // [32][64] swz
  __shared__ __align__(16) short Bs[2][6144];  // [96][64] swz
  int sw8 = (((l & 7) ^ ((l >> 3) & 7)) << 3);  // pre-swizzled chunk for staging
  const ushort_t* asrc0 = xbg + (size_t)(row0 + w * 16 + (l >> 3)) * 1280 + sw8;
  const ushort_t* asrc1 = asrc0 + (size_t)8 * 1280;
  const ushort_t* bsrc[6];
  #pragma unroll
  for (int g = 0; g < 6; ++g)
    bsrc[g] = wcat + (size_t)(w * 48 + g * 8 + (l >> 3)) * 1280 + sw8;

#define QSTAGE(bufi, kk)                                            \
  do {                                                              \
    gload16(asrc0 + (kk), &As[bufi][w * 1024]);                     \
    gload16(asrc1 + (kk), &As[bufi][w * 1024 + 512]);               \
    gload16(bsrc[0] + (kk), &Bs[bufi][w * 3072]);                   \
    gload16(bsrc[1] + (kk), &Bs[bufi][w * 3072 + 512]);             \
    gload16(bsrc[2] + (kk), &Bs[bufi][w * 3072 + 1024]);            \
    gload16(bsrc[3] + (kk), &Bs[bufi][w * 3072 + 1536]);            \
    gload16(bsrc[4] + (kk), &Bs[bufi][w * 3072 + 2048]);            \
    gload16(bsrc[5] + (kk), &Bs[bufi][w * 3072 + 2560]);            \
  } while (0)

  f32x4 acc[6];
  #pragma unroll
  for (int nf = 0; nf < 6; ++nf) acc[nf] = (f32x4){0.f, 0.f, 0.f, 0.f};

  QSTAGE(0, 0);
  int cur = 0;
  for (int t = 0; t < 20; ++t) {
    if (t < 19) {
      QSTAGE(cur ^ 1, (t + 1) * 64);
      VMW(8);
    } else {
      VMW(0);
    }
    BAR();
    #pragma unroll
    for (int ks = 0; ks < 2; ++ks) {
      short8 af = *(const short8*)&As[cur][(w * 16 + l15) * 64 +
                                           (((ks * 4 + l4) ^ (l15 & 7)) << 3)];
      #pragma unroll
      for (int nf = 0; nf < 6; ++nf) {
        short8 bf = *(const short8*)&Bs[cur][(nf * 16 + l15) * 64 +
                                             (((ks * 4 + l4) ^ (l15 & 7)) << 3)];
        acc[nf] = __builtin_amdgcn_mfma_f32_16x16x32_bf16(af, bf, acc[nf], 0, 0, 0);
      }
    }
    BAR();
    cur ^= 1;
  }
#undef QSTAGE

  #pragma unroll
  for (int nf = 0; nf < 6; ++nf) {
    int o = nf * 16 + l15;
    #pragma unroll
    for (int reg = 0; reg < 4; ++reg) {
      int gr = row0 + w * 16 + l4 * 4 + reg;
      int b = (gr >= SP) ? 1 : 0;
      int i = gr - b * SP;
      if (i < Ss) {
        float v = acc[nf][reg];
        if (o < 32) xpq[((size_t)b * Ss + i) * 32 + o] = v;
        else if (o < 64) k1b[((size_t)b * SP + i) * 32 + (o - 32)] = f2bf(v);
        else v1b[((size_t)b * 32 + (o - 64)) * SP + i] = f2bf(v);
      }
    }
  }
}

// merged: blockIdx.y<20 -> qh (per i-tile,h,b); blockIdx.y==20 -> kb (per j-tile,b)
__global__ void qh_kb_kernel(const float* __restrict__ xpq, const float* __restrict__ wm,
                             const float* __restrict__ b2s, const ushort_t* __restrict__ k1b,
                             ushort_t* __restrict__ qhb, float* __restrict__ kbp) {
  int tid = threadIdx.x, b = blockIdx.z;
  if (blockIdx.y == 20) {
    int j0 = blockIdx.x * 64;
    __shared__ float k1s[64 * 33];
    __shared__ float b2sh[20 * 33];
    for (int e = tid; e < 2048; e += 256) {
      int row = e >> 5, t = e & 31;
      k1s[row * 33 + t] = bf2f(k1b[((size_t)b * SP + j0 + row) * 32 + t]);
    }
    for (int e = tid; e < 640; e += 256) b2sh[(e >> 5) * 33 + (e & 31)] = b2s[e];
    __syncthreads();
    for (int e = tid; e < 1280; e += 256) {
      int h = e >> 6, rw = e & 63;
      int j = j0 + rw;
      float s = -1e30f;
      if (j < Ss) {
        s = 0.f;
        #pragma unroll 8
        for (int t = 0; t < 32; ++t) s += k1s[rw * 33 + t] * b2sh[h * 33 + t];
      }
      kbp[((size_t)b * Hh + h) * SP + j] = s;
    }
  } else {
    int it = blockIdx.x, h = blockIdx.y;
    int i0 = it * 64;
    __shared__ float q1s[64 * 33];
    __shared__ float wms[1024];
    for (int e = tid; e < 2048; e += 256) {
      int row = e >> 5, r = e & 31;
      int i = i0 + row;
      q1s[row * 33 + r] = (i < Ss) ? xpq[((size_t)b * Ss + i) * 32 + r] : 0.f;
    }
    for (int e = tid; e < 1024; e += 256) wms[e] = wm[h * 1024 + e];
    __syncthreads();
    int row = tid >> 2, tc = (tid & 3) * 8;
    float o[8];
    #pragma unroll
    for (int j = 0; j < 8; ++j) o[j] = 0.f;
    for (int r = 0; r < 32; ++r) {
      float qv = q1s[row * 33 + r];
      #pragma unroll
      for (int j = 0; j < 8; ++j) o[j] += qv * wms[r * 32 + tc + j];
    }
    short8 sv;
    #pragma unroll
    for (int j = 0; j < 8; ++j) sv[j] = (short)f2bf(o[j]);
    *(short8*)(qhb + ((size_t)(b * Hh + h) * SP + i0 + row) * 32 + tc) = sv;
  }
}

// Attention: round-10 verified loop body; this round's delta:
//  - 8 waves / 512 threads / 128 queries per block (grid 12x20x2 = 480 blocks).
//    Waves 0-3 stage K/V/kb (as before); waves 4-7 compute only. Barrier
//    publishes staged data to all waves (same mechanism as kbS from w0).
__global__ __launch_bounds__(512) void attn2_kernel(
    const ushort_t* __restrict__ qhg, const ushort_t* __restrict__ k1g,
    const ushort_t* __restrict__ v1g, const ushort_t* __restrict__ wv2g,
    const float* __restrict__ kbg, const float* __restrict__ bv, ushort_t* __restrict__ wvb) {
  int it = blockIdx.x, h = blockIdx.y, b = blockIdx.z;
  int bh = b * Hh + h;
  int i0 = it * 128;
  int tid = threadIdx.x, w = tid >> 6, l = tid & 63;
  int l15 = l & 15, l4 = l >> 4;

  __shared__ short kS[3][2048];  // [kchunk(4)][key(64)][8]
  __shared__ short vS[3][2048];  // [r(32)][jslot(8)^swz][8]
  __shared__ float kbS[3][64];
  __shared__ short pS[8][1024];  // per-wave P [q(16)][key-slot swz]
  __shared__ short p2S[8][512];  // per-wave PV1 [q(16)][r-slot swz]

  // resident A-frag: Qh[q=l15][k=l4*8+e]  (wave w owns queries i0+w*16..+15)
  short8 qa = *(const short8*)(qhg + ((size_t)bh * SP + i0 + w * 16 + l15) * 32 + l4 * 8);
  // resident B-frags: Wv2h[r=l4*8+e][d=db*16+l15]
  short8 wb0 = *(const short8*)(wv2g + (size_t)(h * 64 + 0 * 16 + l15) * 32 + l4 * 8);
  short8 wb1 = *(const short8*)(wv2g + (size_t)(h * 64 + 1 * 16 + l15) * 32 + l4 * 8);
  short8 wb2 = *(const short8*)(wv2g + (size_t)(h * 64 + 2 * 16 + l15) * 32 + l4 * 8);
  short8 wb3 = *(const short8*)(wv2g + (size_t)(h * 64 + 3 * 16 + l15) * 32 + l4 * 8);
  VMW(0);  // residents landed; manual vmcnt counting below is exact

  // staging sources: only waves 0-3 use these (quarter index = w)
  const ushort_t* ksrc = k1g + (size_t)b * SP * 32 + l * 32 + (w & 3) * 8;
  const ushort_t* vsrc = v1g + ((size_t)b * 32 + (w & 3) * 8 + (l >> 3)) * SP +
                         (((l & 7) ^ ((l >> 3) & 7)) << 3);
  const float* kbsrc = kbg + (size_t)bh * SP + l;

#define STAGE(bufi, tt)                                         \
  do {                                                          \
    if (w < 4) {                                                \
      int j0s = (tt) * 64;                                      \
      gload16(ksrc + (size_t)j0s * 32, &kS[bufi][w * 512]);     \
      gload16(vsrc + j0s, &vS[bufi][w * 512]);                  \
      if (w == 0) gload4(kbsrc + j0s, &kbS[bufi][0]);           \
    }                                                           \
  } while (0)

  STAGE(0, 0);
  STAGE(1, 1);

  f32x4 pv1[2];
  pv1[0] = (f32x4){0.f, 0.f, 0.f, 0.f};
  pv1[1] = (f32x4){0.f, 0.f, 0.f, 0.f};
  float psr[4] = {0.f, 0.f, 0.f, 0.f};
  const f32x4 zf = (f32x4){0.f, 0.f, 0.f, 0.f};

  int cur = 0;   // compute buffer = t % 3
  for (int t = 0; t < NT; ++t) {
    // in flight (staging waves): stages {t, t+1}; wait stage t, leave t+1.
    if (t < NT - 1) {
      if (w == 0) VMW(3);
      else if (w < 4) VMW(2);
    } else {
      if (w < 4) VMW(0);
    }
    BAR();

    __builtin_amdgcn_s_setprio(1);
    // S = Qh @ K1^T (+kb), exp2, pack to per-wave P (b16 low-half writes)
    #pragma unroll
    for (int nb = 0; nb < 4; ++nb) {
      short8 kf = *(const short8*)&kS[cur][l4 * 512 + (nb * 16 + l15) * 8];
      f32x4 c = __builtin_amdgcn_mfma_f32_16x16x32_bf16(qa, kf, zf, 0, 0, 0);
      float kbv = kbS[cur][nb * 16 + l15];
      int slot_lo = nb * 2 + (l15 >> 3);
      #pragma unroll
      for (int reg = 0; reg < 4; ++reg) {
        int q = l4 * 4 + reg;
        float p = fexp2(c[reg] + kbv);
        psr[reg] += p;
        pS[w][q * 64 + ((slot_lo ^ (q & 7)) << 3) + (l15 & 7)] = (short)cvtpk(p, p);
      }
    }

    // PV1 += P @ v1 (16q x 32r), fp32 accumulation across all tiles
    #pragma unroll
    for (int kh = 0; kh < 2; ++kh) {
      short8 pa = *(const short8*)&pS[w][l15 * 64 + (((kh * 4 + l4) ^ (l15 & 7)) << 3)];
      #pragma unroll
      for (int nf = 0; nf < 2; ++nf) {
        short8 vf =
            *(const short8*)&vS[cur][(nf * 16 + l15) * 64 + (((kh * 4 + l4) ^ (l15 & 7)) << 3)];
        pv1[nf] = __builtin_amdgcn_mfma_f32_16x16x32_bf16(pa, vf, pv1[nf], 0, 0, 0);
      }
    }
    __builtin_amdgcn_s_setprio(0);

    // stage tile t+2 into the buffer compute(t-1) vacated (all waves passed BAR(t))
    if (t + 2 < NT) {
      int sb = (cur + 2 >= 3) ? cur - 1 : cur + 2;
      STAGE(sb, t + 2);
    }
    cur = (cur == 2) ? 0 : cur + 1;
  }
#undef STAGE

  // epilogue: relayout PV1 -> A-frag via per-wave LDS (once), then PV2
  #pragma unroll
  for (int nf = 0; nf < 2; ++nf) {
    #pragma unroll
    for (int reg = 0; reg < 4; ++reg) {
      int q = l4 * 4 + reg;
      int slot = nf * 2 + (l15 >> 3);
      p2S[w][q * 32 + ((slot ^ ((q >> 1) & 3)) << 3) + (l15 & 7)] =
          (short)cvtpk(pv1[nf][reg], pv1[nf][reg]);
    }
  }
  short8 pa2 = *(const short8*)&p2S[w][l15 * 32 + ((l4 ^ ((l15 >> 1) & 3)) << 3)];

  f32x4 acc[4];
  acc[0] = __builtin_amdgcn_mfma_f32_16x16x32_bf16(pa2, wb0, zf, 0, 0, 0);
  acc[1] = __builtin_amdgcn_mfma_f32_16x16x32_bf16(pa2, wb1, zf, 0, 0, 0);
  acc[2] = __builtin_amdgcn_mfma_f32_16x16x32_bf16(pa2, wb2, zf, 0, 0, 0);
  acc[3] = __builtin_amdgcn_mfma_f32_16x16x32_bf16(pa2, wb3, zf, 0, 0, 0);

  #pragma unroll
  for (int reg = 0; reg < 4; ++reg) {
    #pragma unroll
    for (int m = 1; m < 16; m <<= 1) psr[reg] += __shfl_xor(psr[reg], m, 64);
  }
  float inv[4];
  #pragma unroll
  for (int reg = 0; reg < 4; ++reg) inv[reg] = 1.f / psr[reg];

  #pragma unroll
  for (int db = 0; db < 4; ++db) {
    float bvv = bv[h * 64 + db * 16 + l15];
    #pragma unroll
    for (int reg = 0; reg < 4; ++reg) {
      int qi = i0 + w * 16 + l4 * 4 + reg;
      if (qi < Ss)
        wvb[((size_t)(b * SP + qi)) * 1280 + h * 64 + db * 16 + l15] =
            f2bf(acc[db][reg] * inv[reg] + bvv);
    }
  }
}

// GEMM: wvb[3072x1280]bf16 @ wo1b[32x1280]^T -> tbuf fp32, rowtile 32, BK=64
__global__ __launch_bounds__(128) void gemm_o1_kernel(const ushort_t* __restrict__ wvg,
                                                      const ushort_t* __restrict__ wo1,
                                                      float* __restrict__ tbuf) {
  int tid = threadIdx.x, w = tid >> 6, l = tid & 63, l15 = l & 15, l4 = l >> 4;
  int row0 = blockIdx.x * 32;
  __shared__ __align__(16) short As[2][2048];
  __shared__ __align__(16) short Bs[2][2048];
  int sw8 = (((l & 7) ^ ((l >> 3) & 7)) << 3);
  const ushort_t* asrc0 = wvg + (size_t)(row0 + w * 16 + (l >> 3)) * 1280 + sw8;
  const ushort_t* asrc1 = asrc0 + (size_t)8 * 1280;
  const ushort_t* bsrc = wo1 + (size_t)(w * 16 + (l >> 3)) * 1280 + sw8;
  const ushort_t* bsrc1 = bsrc + (size_t)8 * 1280;

#define OSTAGE(bufi, kk)                                 \
  do {                                                   \
    gload16(asrc0 + (kk), &As[bufi][w * 1024]);          \
    gload16(asrc1 + (kk), &As[bufi][w * 1024 + 512]);    \
    gload16(bsrc + (kk), &Bs[bufi][w * 1024]);           \
    gload16(bsrc1 + (kk), &Bs[bufi][w * 1024 + 512]);    \
  } while (0)

  f32x4 acc[2];
  acc[0] = (f32x4){0.f, 0.f, 0.f, 0.f};
  acc[1] = (f32x4){0.f, 0.f, 0.f, 0.f};
  OSTAGE(0, 0);
  int cur = 0;
  for (int t = 0; t < 20; ++t) {
    if (t < 19) {
      OSTAGE(cur ^ 1, (t + 1) * 64);
      VMW(4);
    } else {
      VMW(0);
    }
    BAR();
    #pragma unroll
    for (int ks = 0; ks < 2; ++ks) {
      short8 af = *(const short8*)&As[cur][(w * 16 + l15) * 64 +
                                           (((ks * 4 + l4) ^ (l15 & 7)) << 3)];
      #pragma unroll
      for (int nf = 0; nf < 2; ++nf) {
        short8 bf = *(const short8*)&Bs[cur][(nf * 16 + l15) * 64 +
                                             (((ks * 4 + l4) ^ (l15 & 7)) << 3)];
        acc[nf] = __builtin_amdgcn_mfma_f32_16x16x32_bf16(af, bf, acc[nf], 0, 0, 0);
      }
    }
    BAR();
    cur ^= 1;
  }
#undef OSTAGE

  #pragma unroll
  for (int nf = 0; nf < 2; ++nf) {
    int o = nf * 16 + l15;
    #pragma unroll
    for (int reg = 0; reg < 4; ++reg) {
      int gr = row0 + w * 16 + l4 * 4 + reg;
      int b = (gr >= SP) ? 1 : 0;
      int i = gr - b * SP;
      if (i < Ss) tbuf[((size_t)b * Ss + i) * 32 + o] = acc[nf][reg];
    }
  }
}

// out[row][n] = bo[n] + sum_o tbuf[row][o] * Wo2[n][o]
__global__ void proj_o2_kernel(const float* __restrict__ tbuf, const float* __restrict__ Wo2,
                               const float* __restrict__ bo, float* __restrict__ out) {
  int rb = blockIdx.x, nb = blockIdx.y, tid = threadIdx.x;
  int rowbase = rb * 16, n0 = nb * 256;
  __shared__ float ts[16 * 33];
  __shared__ float wos[256 * 33];
  for (int e = tid; e < 8192; e += 256) {
    int nloc = e >> 5, o = e & 31;
    wos[nloc * 33 + o] = Wo2[(size_t)(n0 + nloc) * 32 + o];
  }
  for (int e = tid; e < 512; e += 256) {
    int row = e >> 5, o = e & 31;
    int gr = rowbase + row;
    ts[row * 33 + o] = (gr < Bb * Ss) ? tbuf[(size_t)gr * 32 + o] : 0.f;
  }
  __syncthreads();
  int n = n0 + tid;
  float bias = bo[n];
  for (int row = 0; row < 16; ++row) {
    int gr = rowbase + row;
    if (gr >= Bb * Ss) break;
    float s = bias;
    #pragma unroll 8
    for (int o = 0; o < 32; ++o) s += ts[row * 33 + o] * wos[tid * 33 + o];
    out[(size_t)gr * 1280 + n] = s;
  }
}

extern "C" void kernel_launch(void* const* d_in, const int* in_sizes, int n_in,
                              void* d_out, int out_size, void* d_ws, size_t ws_size,
                              hipStream_t stream) {
  const float* x   = (const float*)d_in[0];
  const float* Wq1 = (const float*)d_in[1];
  const float* Wq2 = (const float*)d_in[2];
  const float* bq  = (const float*)d_in[3];
  const float* Wk1 = (const float*)d_in[4];
  const float* Wk2 = (const float*)d_in[5];
  // d_in[6] = bk : drops out of softmax (row-constant logit shift)
  const float* Wv1 = (const float*)d_in[7];
  const float* Wv2 = (const float*)d_in[8];
  const float* bv  = (const float*)d_in[9];
  const float* Wo1 = (const float*)d_in[10];
  const float* Wo2 = (const float*)d_in[11];
  const float* bo  = (const float*)d_in[12];
  float* out = (float*)d_out;
  float* ws  = (float*)d_ws;

  if (ws_size < (size_t)5431424 * sizeof(float)) return;

  float* wm    = ws;
  float* b2s   = ws + 20480;
  float* xpq   = ws + 21120;
  float* kb    = ws + 117120;
  float* tbuf  = ws + 178560;
  ushort_t* qhb   = (ushort_t*)(ws + 274560);
  ushort_t* k1b   = (ushort_t*)(ws + 1257600);
  ushort_t* v1b   = (ushort_t*)(ws + 1306752);
  ushort_t* xb    = (ushort_t*)(ws + 1355904);
  ushort_t* wcatb = (ushort_t*)(ws + 3321984);
  ushort_t* wo1b  = (ushort_t*)(ws + 3403904);
  ushort_t* wv2b  = (ushort_t*)(ws + 3444864);
  ushort_t* wvb   = (ushort_t*)(ws + 3465344);

  prep_kernel<<<2080, 256, 0, stream>>>(x, Wq1, Wk1, Wv1, Wo1, Wq2, Wk2, Wv2, bq,
                                        xb, wcatb, wo1b, wv2b, wm, b2s);
  gemm_qkv_kernel<<<96, 128, 0, stream>>>(xb, wcatb, xpq, k1b, v1b);
  qh_kb_kernel<<<dim3(NT, 21, Bb), 256, 0, stream>>>(xpq, wm, b2s, k1b, qhb, kb);
  attn2_kernel<<<dim3(12, Hh, Bb), 512, 0, stream>>>(qhb, k1b, v1b, wv2b, kb, bv, wvb);
  gemm_o1_kernel<<<96, 128, 0, stream>>>(wvb, wo1b, tbuf);
  proj_o2_kernel<<<dim3(188, 5), 256, 0, stream>>>(tbuf, Wo2, bo, out);
}